// Round 5
// baseline (376.080 us; speedup 1.0000x reference)
//
#include <hip/hip_runtime.h>

#define LL 64
#define DD 1024
#define HH 512
#define SS 50000
#define VV 40000
#define KD 32
#define MM 128  // B*L

typedef __bf16 bf16_t;
typedef __bf16 bf16x8 __attribute__((ext_vector_type(8)));
typedef __bf16 bf16x4 __attribute__((ext_vector_type(4)));
typedef __bf16 bf16x2 __attribute__((ext_vector_type(2)));
typedef float f32x4 __attribute__((ext_vector_type(4)));

// ---------------- Kernel 1: BatchNorm over (B, D) per l; write xn bf16 [128][1024]
__global__ __launch_bounds__(256) void k_bn(const float* __restrict__ x,
        const float* __restrict__ gamma, const float* __restrict__ beta,
        bf16_t* __restrict__ xn) {
    int l = blockIdx.x;        // 0..63
    int t = threadIdx.x;       // 0..255
    int b = t >> 7;            // 0..1
    int d0 = (t & 127) << 3;   // 8 elems/thread
    const float* xp = x + (size_t)(b * LL + l) * DD + d0;
    float4 v0 = *(const float4*)xp;
    float4 v1 = *(const float4*)(xp + 4);
    float s  = v0.x + v0.y + v0.z + v0.w + v1.x + v1.y + v1.z + v1.w;
    float ss = v0.x*v0.x + v0.y*v0.y + v0.z*v0.z + v0.w*v0.w
             + v1.x*v1.x + v1.y*v1.y + v1.z*v1.z + v1.w*v1.w;
    #pragma unroll
    for (int off = 32; off > 0; off >>= 1) {
        s  += __shfl_xor(s, off);
        ss += __shfl_xor(ss, off);
    }
    __shared__ float red[8];
    int wv = t >> 6, ln = t & 63;
    if (ln == 0) { red[wv] = s; red[4 + wv] = ss; }
    __syncthreads();
    float tot  = red[0] + red[1] + red[2] + red[3];
    float tots = red[4] + red[5] + red[6] + red[7];
    float mean = tot * (1.0f / 2048.0f);
    float var  = tots * (1.0f / 2048.0f) - mean * mean;
    float rstd = rsqrtf(var + 1e-5f);
    float g   = gamma[l] * rstd;
    float ofs = beta[l] - mean * g;
    bf16x8 o;
    o[0] = (bf16_t)(v0.x * g + ofs);
    o[1] = (bf16_t)(v0.y * g + ofs);
    o[2] = (bf16_t)(v0.z * g + ofs);
    o[3] = (bf16_t)(v0.w * g + ofs);
    o[4] = (bf16_t)(v1.x * g + ofs);
    o[5] = (bf16_t)(v1.y * g + ofs);
    o[6] = (bf16_t)(v1.z * g + ofs);
    o[7] = (bf16_t)(v1.w * g + ofs);
    *(bf16x8*)(xn + (size_t)(b * LL + l) * DD + d0) = o;
}

// ---------------- Kernel 2: h = relu(xn @ W1 + b1), bf16 [128][512]
// 256 blocks x 1 wave; W1 re-reads hit L2 (W1 = 2 MB).
__global__ __launch_bounds__(64) void k_gemm1(const bf16_t* __restrict__ xn,
        const float* __restrict__ W1, const float* __restrict__ b1,
        bf16_t* __restrict__ h) {
    int lane = threadIdx.x & 63;
    int c = lane & 15, q = lane >> 4;
    int tile = blockIdx.x;           // 256 tiles: 8 m x 32 n
    int tm = tile >> 5, tn = tile & 31;
    int col = tn * 16 + c;
    f32x4 acc = {};
    #pragma unroll 2
    for (int kk = 0; kk < DD; kk += 32) {
        bf16x8 afr = *(const bf16x8*)(xn + (size_t)(tm * 16 + c) * DD + kk + q * 8);
        bf16x8 bfr;
        #pragma unroll
        for (int j = 0; j < 8; ++j)
            bfr[j] = (bf16_t)W1[(size_t)(kk + q * 8 + j) * HH + col];
        acc = __builtin_amdgcn_mfma_f32_16x16x32_bf16(afr, bfr, acc, 0, 0, 0);
    }
    float bias = b1[col];
    #pragma unroll
    for (int r = 0; r < 4; ++r) {
        int m = tm * 16 + q * 4 + r;   // C/D: col=lane&15, row=q*4+r  [m89]
        float v = acc[r] + bias;
        h[(size_t)m * HH + col] = (bf16_t)(v > 0.f ? v : 0.f);
    }
}

// ---------------- no-LDS TLP-streaming GEMM core ----------------
// Wave owns 16 output cols (col = per-lane absolute column, pre-clamped).
// Per 32-k step: 8 scalar fp32 W loads (wave-coalesced 64B segments) -> cvt,
// 8x 16B A loads (L2-resident h), 8 MFMA. No LDS, no barriers: latency hidden
// by ~12 free-running waves/CU (fillBuffer regime).
template<int WC, int KSTEPS>
__device__ __forceinline__ void gemm_nolds(const bf16_t* __restrict__ A, int lda,
        const float* __restrict__ Wc /* = W + col */, int q, int c,
        f32x4 (&acc)[8]) {
    #pragma unroll 2
    for (int st = 0; st < KSTEPS; ++st) {
        const float* wp = Wc + (size_t)(st * 32 + q * 8) * WC;
        bf16x8 bfr;
        #pragma unroll
        for (int j = 0; j < 8; ++j)
            bfr[j] = (bf16_t)wp[(size_t)j * WC];
        const bf16_t* ap = A + (size_t)c * lda + st * 32 + q * 8;
        #pragma unroll
        for (int ms = 0; ms < 8; ++ms) {
            bf16x8 afr = *(const bf16x8*)(ap + (size_t)(ms * 16) * lda);
            acc[ms] = __builtin_amdgcn_mfma_f32_16x16x32_bf16(afr, bfr, acc[ms], 0, 0, 0);
        }
    }
}

// ---------------- Kernel 3: vT[col][m] = bf16(h @ W_slm + b_slm), transposed
__global__ __launch_bounds__(256) void k_gemm_v(const bf16_t* __restrict__ h,
        const float* __restrict__ Wslm, const float* __restrict__ bslm,
        bf16_t* __restrict__ vT) {
    int t = threadIdx.x, wv = t >> 6, lane = t & 63;
    int c = lane & 15, q = lane >> 4;
    int col = blockIdx.x * 64 + wv * 16 + c;   // 625*64 = 40000 exact
    f32x4 acc[8] = {};
    gemm_nolds<VV, 16>(h, HH, Wslm + col, q, c, acc);
    float bias = bslm[col];
    #pragma unroll
    for (int ms = 0; ms < 8; ++ms) {
        bf16x4 o;
        #pragma unroll
        for (int rr = 0; rr < 4; ++rr) o[rr] = (bf16_t)(acc[ms][rr] + bias);
        *(bf16x4*)(vT + (size_t)col * MM + ms * 16 + q * 4) = o;
    }
}

// ---------------- Kernel 4: gather — one wave per s, lane owns 2 m-values.
// slm[s][m] (bf16) = sum_k w[s,k] * vT[idx[s,k]][m]
__global__ __launch_bounds__(256) void k_gather(const bf16_t* __restrict__ vT,
        const float* __restrict__ slw, const int* __restrict__ slidx,
        bf16_t* __restrict__ slm) {
    int t = threadIdx.x;
    int wv = t >> 6, lane = t & 63;
    int s = blockIdx.x * 4 + wv;        // 50000 = 12500*4, exact
    int idv = slidx[(size_t)s * KD + (lane & 31)];
    float wgt = slw[(size_t)s * KD + (lane & 31)];
    unsigned int u[KD];
    #pragma unroll
    for (int k = 0; k < KD; ++k) {
        int id = __shfl(idv, k);
        u[k] = *(const unsigned int*)(vT + (size_t)id * MM + lane * 2);
    }
    float a0 = 0.f, a1 = 0.f;
    #pragma unroll
    for (int k = 0; k < KD; ++k) {
        float w = __shfl(wgt, k);
        a0 += w * __uint_as_float(u[k] << 16);
        a1 += w * __uint_as_float(u[k] & 0xffff0000u);
    }
    bf16x2 o;
    o[0] = (bf16_t)a0;
    o[1] = (bf16_t)a1;
    *(bf16x2*)(slm + (size_t)s * MM + lane * 2) = o;
}

// ---------------- Kernel 5: out = h @ W2 + b2 + 0.1 * slm^T
__global__ __launch_bounds__(256) void k_gemm_y(const bf16_t* __restrict__ h,
        const float* __restrict__ W2, const float* __restrict__ b2,
        const bf16_t* __restrict__ slm, float* __restrict__ out) {
    int t = threadIdx.x, wv = t >> 6, lane = t & 63;
    int c = lane & 15, q = lane >> 4;
    int col = blockIdx.x * 64 + wv * 16 + c;   // 782*64 = 50048 (padded)
    int lcol = col < SS ? col : SS - 1;        // clamp W reads in last block
    f32x4 acc[8] = {};
    gemm_nolds<SS, 16>(h, HH, W2 + lcol, q, c, acc);
    if (col < SS) {
        float bias = b2[col];
        #pragma unroll
        for (int ms = 0; ms < 8; ++ms) {
            bf16x4 sv = *(const bf16x4*)(slm + (size_t)col * MM + ms * 16 + q * 4);
            #pragma unroll
            for (int rr = 0; rr < 4; ++rr) {
                int m = ms * 16 + q * 4 + rr;
                out[(size_t)m * SS + col] = acc[ms][rr] + bias + 0.1f * (float)sv[rr];
            }
        }
    }
}

extern "C" void kernel_launch(void* const* d_in, const int* in_sizes, int n_in,
                              void* d_out, int out_size, void* d_ws, size_t ws_size,
                              hipStream_t stream) {
    const float* x     = (const float*)d_in[0];
    const float* gamma = (const float*)d_in[1];
    const float* beta  = (const float*)d_in[2];
    const float* W1    = (const float*)d_in[3];
    const float* b1    = (const float*)d_in[4];
    const float* W2    = (const float*)d_in[5];
    const float* b2    = (const float*)d_in[6];
    const float* Wslm  = (const float*)d_in[7];
    const float* bslm  = (const float*)d_in[8];
    const float* slw   = (const float*)d_in[9];
    const int*   slidx = (const int*)d_in[10];
    float* out = (float*)d_out;

    char* ws = (char*)d_ws;
    bf16_t* xn  = (bf16_t*)ws;                     // 128*1024*2  = 262144 B
    bf16_t* h   = (bf16_t*)(ws + 262144);          // 128*512*2   = 131072 B
    bf16_t* vT  = (bf16_t*)(ws + 393216);          // 40000*128*2 = 10240000 B
    bf16_t* slm = (bf16_t*)(ws + 10633216);        // 50000*128*2 = 12800000 B

    k_bn    <<<64,    256, 0, stream>>>(x, gamma, beta, xn);
    k_gemm1 <<<256,   64,  0, stream>>>(xn, W1, b1, h);
    k_gemm_v<<<625,   256, 0, stream>>>(h, Wslm, bslm, vT);
    k_gather<<<12500, 256, 0, stream>>>(vT, slw, slidx, slm);
    k_gemm_y<<<782,   256, 0, stream>>>(h, W2, b2, slm, out);
}

// Round 7
// 336.930 us; speedup vs baseline: 1.1162x; 1.1162x over previous
//
#include <hip/hip_runtime.h>

#define LL 64
#define DD 1024
#define HH 512
#define SS 50000
#define VV 40000
#define KD 32
#define MM 128  // B*L

typedef __bf16 bf16_t;
typedef __bf16 bf16x8 __attribute__((ext_vector_type(8)));
typedef __bf16 bf16x4 __attribute__((ext_vector_type(4)));
typedef __bf16 bf16x2 __attribute__((ext_vector_type(2)));
typedef float f32x4 __attribute__((ext_vector_type(4)));

__device__ __forceinline__ void async_ld16(const void* g, void* l) {
    __builtin_amdgcn_global_load_lds(
        (const __attribute__((address_space(1))) void*)g,
        (__attribute__((address_space(3))) void*)l, 16, 0, 0);
}

#define WAITV(N) asm volatile("s_waitcnt vmcnt(" #N ")" ::: "memory")

// ---------------- BatchNorm: stats over (B,D) per l; xn bf16 [128][1024]
__global__ __launch_bounds__(256) void k_bn(const float* __restrict__ x,
        const float* __restrict__ gamma, const float* __restrict__ beta,
        bf16_t* __restrict__ xn) {
    int l = blockIdx.x;
    int t = threadIdx.x;
    int b = t >> 7;
    int d0 = (t & 127) << 3;
    const float* xp = x + (size_t)(b * LL + l) * DD + d0;
    float4 v0 = *(const float4*)xp;
    float4 v1 = *(const float4*)(xp + 4);
    float s  = v0.x + v0.y + v0.z + v0.w + v1.x + v1.y + v1.z + v1.w;
    float ss = v0.x*v0.x + v0.y*v0.y + v0.z*v0.z + v0.w*v0.w
             + v1.x*v1.x + v1.y*v1.y + v1.z*v1.z + v1.w*v1.w;
    #pragma unroll
    for (int off = 32; off > 0; off >>= 1) {
        s  += __shfl_xor(s, off);
        ss += __shfl_xor(ss, off);
    }
    __shared__ float red[8];
    int wv = t >> 6, ln = t & 63;
    if (ln == 0) { red[wv] = s; red[4 + wv] = ss; }
    __syncthreads();
    float tot  = red[0] + red[1] + red[2] + red[3];
    float tots = red[4] + red[5] + red[6] + red[7];
    float mean = tot * (1.0f / 2048.0f);
    float var  = tots * (1.0f / 2048.0f) - mean * mean;
    float rstd = rsqrtf(var + 1e-5f);
    float g   = gamma[l] * rstd;
    float ofs = beta[l] - mean * g;
    bf16x8 o;
    o[0] = (bf16_t)(v0.x * g + ofs);
    o[1] = (bf16_t)(v0.y * g + ofs);
    o[2] = (bf16_t)(v0.z * g + ofs);
    o[3] = (bf16_t)(v0.w * g + ofs);
    o[4] = (bf16_t)(v1.x * g + ofs);
    o[5] = (bf16_t)(v1.y * g + ofs);
    o[6] = (bf16_t)(v1.z * g + ofs);
    o[7] = (bf16_t)(v1.w * g + ofs);
    *(bf16x8*)(xn + (size_t)(b * LL + l) * DD + d0) = o;
}

// ---------------- pack: W fp32 [512][NC] -> bf16, per-64col-group contiguous.
// Output unit: group g (64 cols) x step s (32 k): 4 KB block of 256 16B chunks,
// chunk cid=(wv*64+q*16+c) holds W[s*32+q*8 .. +8][g*64+wv*16+c].
// Reads: 1 KB/wave contiguous row segments. Writes: 1 KB/wave contiguous.
__device__ __forceinline__ void pack_body(const float* __restrict__ src,
        bf16_t* __restrict__ dst, int NC, int p, int s) {
    __shared__ __align__(16) char tile[16384];   // [32 rows][256 cols] bf16, swizzled
    int t = threadIdx.x;
    #pragma unroll
    for (int r = 0; r < 8; ++r) {
        int idx = r * 256 + t;
        int row = idx >> 6;            // 0..31 (uniform per wave)
        int colq = (idx & 63) << 2;    // 0..252
        int col = p * 256 + colq;
        bf16x4 o4 = {};
        if (col + 3 < NC) {
            float4 v = *(const float4*)(src + (size_t)(s * 32 + row) * NC + col);
            o4[0] = (bf16_t)v.x; o4[1] = (bf16_t)v.y;
            o4[2] = (bf16_t)v.z; o4[3] = (bf16_t)v.w;
        }
        int qq = row >> 3;
        int swz = ((qq & 1) << 6) | ((qq & 2) << 4);
        *(bf16x4*)(tile + ((row * 512 + colq * 2) ^ swz)) = o4;
    }
    __syncthreads();
    int c = t & 15, q = (t >> 4) & 3, wv = t >> 6;
    int swz = ((q & 1) << 6) | ((q & 2) << 4);
    #pragma unroll
    for (int gl = 0; gl < 4; ++gl) {
        int col2 = gl * 64 + wv * 16 + c;
        bf16x8 o;
        #pragma unroll
        for (int j = 0; j < 8; ++j)
            o[j] = *(const bf16_t*)(tile + ((((q * 8 + j) * 512) + col2 * 2) ^ swz));
        int g = p * 4 + gl;
        *(bf16x8*)(dst + ((size_t)(g * 16 + s) * 256 + t) * 8) = o;
    }
}

// ---------------- gemm1 body (round-0): h = relu(xn @ W1 + b1)
__device__ __forceinline__ void gemm1_body(const bf16_t* __restrict__ xn,
        const float* __restrict__ W1, const float* __restrict__ b1,
        bf16_t* __restrict__ h, int bid) {
    int t = threadIdx.x;
    int wv = t >> 6, lane = t & 63;
    int c = lane & 15, q = lane >> 4;
    int tile = bid * 4 + wv;         // 256 tiles: 8 m x 32 n
    int tm = tile >> 5, tn = tile & 31;
    int col = tn * 16 + c;
    f32x4 acc = {};
    #pragma unroll 2
    for (int kk = 0; kk < DD; kk += 32) {
        bf16x8 afr = *(const bf16x8*)(xn + (size_t)(tm * 16 + c) * DD + kk + q * 8);
        bf16x8 bfr;
        #pragma unroll
        for (int j = 0; j < 8; ++j)
            bfr[j] = (bf16_t)W1[(size_t)(kk + q * 8 + j) * HH + col];
        acc = __builtin_amdgcn_mfma_f32_16x16x32_bf16(afr, bfr, acc, 0, 0, 0);
    }
    float bias = b1[col];
    #pragma unroll
    for (int r = 0; r < 4; ++r) {
        int m = tm * 16 + q * 4 + r;   // C/D: col=lane&15, row=q*4+r  [m89]
        float v = acc[r] + bias;
        h[(size_t)m * HH + col] = (bf16_t)(v > 0.f ? v : 0.f);
    }
}

// ---------------- Kernel 2: gemm1 (64 blocks) || pack Wslm (2512 blocks)
__global__ __launch_bounds__(256) void k_g1_packv(const bf16_t* __restrict__ xn,
        const float* __restrict__ W1, const float* __restrict__ b1,
        bf16_t* __restrict__ h, const float* __restrict__ Wslm,
        bf16_t* __restrict__ Wvp) {
    int bid = blockIdx.x;
    if (bid < 64) { gemm1_body(xn, W1, b1, h, bid); return; }
    int u = bid - 64;                 // 157 p-tiles x 16 steps
    pack_body(Wslm, Wvp, VV, u >> 4, u & 15);
}

// ---------------- pipelined GEMM core: K=512 (16 steps), BN=64/block,
// 4-buffer (48 KB), distance-3 prefetch, counted vmcnt(9). W packed contiguous.
__device__ __forceinline__ void gemm_pipe16(const bf16_t* __restrict__ A,
        const bf16_t* __restrict__ Wg, char* smem, f32x4 (&acc)[8]) {
    int t = threadIdx.x;
    int t2 = t + 256;
    const bf16_t* gh0 = A + (size_t)(((t  >> 6) << 4) + (t  & 15)) * HH + ((t  >> 4) & 3) * 8;
    const bf16_t* gh1 = A + (size_t)(((t2 >> 6) << 4) + (t2 & 15)) * HH + ((t2 >> 4) & 3) * 8;
    const char* wsrc = (const char*)Wg + t * 16;

    #define STAGE16(buf, st) do { \
        char* sb = smem + (buf) * 12288; \
        async_ld16(wsrc + (size_t)(st) * 4096, sb + t * 16); \
        async_ld16(gh0 + (st) * 32, sb + 4096 + t * 16); \
        async_ld16(gh1 + (st) * 32, sb + 4096 + (t + 256) * 16); } while (0)

    STAGE16(0, 0); STAGE16(1, 1); STAGE16(2, 2); STAGE16(3, 3);  // 12 in flight
    int lane = t & 63;
    auto comp = [&](int cur) {
        char* sb = smem + cur * 12288;
        bf16x8 bfr = *(const bf16x8*)(sb + t * 16);          // lane-consecutive
        const bf16_t* al = (const bf16_t*)(sb + 4096);
        #pragma unroll
        for (int ms = 0; ms < 8; ++ms) {
            bf16x8 afr = *(const bf16x8*)(al + (size_t)(ms * 64 + lane) * 8);
            acc[ms] = __builtin_amdgcn_mfma_f32_16x16x32_bf16(afr, bfr, acc[ms], 0, 0, 0);
        }
    };
    #pragma unroll 1
    for (int st = 0; st < 12; ++st) {
        WAITV(9);                       // stage[st] landed; 3 stages stay in flight
        __builtin_amdgcn_s_barrier();
        comp(st & 3);
        __builtin_amdgcn_s_barrier();   // all waves done reading buf before reuse
        STAGE16(st & 3, st + 4);
    }
    WAITV(9); __builtin_amdgcn_s_barrier(); comp(0);   // st=12
    WAITV(6); __builtin_amdgcn_s_barrier(); comp(1);   // st=13
    WAITV(3); __builtin_amdgcn_s_barrier(); comp(2);   // st=14
    WAITV(0); __builtin_amdgcn_s_barrier(); comp(3);   // st=15
    #undef STAGE16
}

// ---------------- Kernel 3: vT[col][m] = bf16(h @ Wslm + bslm)  (packed W)
__global__ __launch_bounds__(256) void k_gemm_v(const bf16_t* __restrict__ h,
        const bf16_t* __restrict__ Wvp, const float* __restrict__ bslm,
        bf16_t* __restrict__ vT) {
    __shared__ __align__(16) char smem[4 * 12288];   // 48 KB
    int bid = blockIdx.x;                            // 625 groups, exact
    f32x4 acc[8] = {};
    gemm_pipe16(h, Wvp + (size_t)bid * 16 * 2048, smem, acc);
    int t = threadIdx.x, wv = t >> 6, lane = t & 63;
    int c = lane & 15, q = lane >> 4;
    int col = bid * 64 + wv * 16 + c;
    float bias = bslm[col];
    #pragma unroll
    for (int ms = 0; ms < 8; ++ms) {
        bf16x4 o;
        #pragma unroll
        for (int rr = 0; rr < 4; ++rr) o[rr] = (bf16_t)(acc[ms][rr] + bias);
        *(bf16x4*)(vT + (size_t)col * MM + ms * 16 + q * 4) = o;
    }
}

// ---------------- gather body (round-1, proven)
__device__ __forceinline__ void gather_body(const bf16_t* __restrict__ vT,
        const float* __restrict__ slw, const int* __restrict__ slidx,
        bf16_t* __restrict__ slm, int bid) {
    int t = threadIdx.x;
    int wv = t >> 6, lane = t & 63;
    int s = bid * 4 + wv;               // 50000 = 12500*4, exact
    int idv = slidx[(size_t)s * KD + (lane & 31)];
    float wgt = slw[(size_t)s * KD + (lane & 31)];
    unsigned int u[KD];
    #pragma unroll
    for (int k = 0; k < KD; ++k) {
        int id = __shfl(idv, k);
        u[k] = *(const unsigned int*)(vT + (size_t)id * MM + lane * 2);
    }
    float a0 = 0.f, a1 = 0.f;
    #pragma unroll
    for (int k = 0; k < KD; ++k) {
        float w = __shfl(wgt, k);
        a0 += w * __uint_as_float(u[k] << 16);
        a1 += w * __uint_as_float(u[k] & 0xffff0000u);
    }
    bf16x2 o;
    o[0] = (bf16_t)a0;
    o[1] = (bf16_t)a1;
    *(bf16x2*)(slm + (size_t)s * MM + lane * 2) = o;
}

// ---------------- Kernel 4: gather (12500) || pack W2 (3136) — L3-bound gather
// overlaps HBM-bound pack; HBM is otherwise idle during gather.
__global__ __launch_bounds__(256) void k_gather_packy(const bf16_t* __restrict__ vT,
        const float* __restrict__ slw, const int* __restrict__ slidx,
        bf16_t* __restrict__ slm, const float* __restrict__ W2,
        bf16_t* __restrict__ W2p) {
    int bid = blockIdx.x;
    if (bid < 12500) { gather_body(vT, slw, slidx, slm, bid); return; }
    int u = bid - 12500;                // 196 p-tiles x 16 steps
    pack_body(W2, W2p, SS, u >> 4, u & 15);
}

// ---------------- Kernel 5: out = h @ W2 + b2 + 0.1 * slm^T   (packed W2)
__global__ __launch_bounds__(256) void k_gemm_y(const bf16_t* __restrict__ h,
        const bf16_t* __restrict__ W2p, const float* __restrict__ b2,
        const bf16_t* __restrict__ slm, float* __restrict__ out) {
    __shared__ __align__(16) char smem[4 * 12288];   // 48 KB
    int bid = blockIdx.x;                            // 782 groups (padded cols 0)
    f32x4 acc[8] = {};
    gemm_pipe16(h, W2p + (size_t)bid * 16 * 2048, smem, acc);
    int t = threadIdx.x, wv = t >> 6, lane = t & 63;
    int c = lane & 15, q = lane >> 4;
    int col = bid * 64 + wv * 16 + c;
    if (col < SS) {
        float bias = b2[col];
        #pragma unroll
        for (int ms = 0; ms < 8; ++ms) {
            bf16x4 sv = *(const bf16x4*)(slm + (size_t)col * MM + ms * 16 + q * 4);
            #pragma unroll
            for (int rr = 0; rr < 4; ++rr) {
                int m = ms * 16 + q * 4 + rr;
                out[(size_t)m * SS + col] = acc[ms][rr] + bias + 0.1f * (float)sv[rr];
            }
        }
    }
}

extern "C" void kernel_launch(void* const* d_in, const int* in_sizes, int n_in,
                              void* d_out, int out_size, void* d_ws, size_t ws_size,
                              hipStream_t stream) {
    const float* x     = (const float*)d_in[0];
    const float* gamma = (const float*)d_in[1];
    const float* beta  = (const float*)d_in[2];
    const float* W1    = (const float*)d_in[3];
    const float* b1    = (const float*)d_in[4];
    const float* W2    = (const float*)d_in[5];
    const float* b2    = (const float*)d_in[6];
    const float* Wslm  = (const float*)d_in[7];
    const float* bslm  = (const float*)d_in[8];
    const float* slw   = (const float*)d_in[9];
    const int*   slidx = (const int*)d_in[10];
    float* out = (float*)d_out;

    char* ws = (char*)d_ws;
    bf16_t* xn  = (bf16_t*)ws;                      // 262,144 B
    bf16_t* h   = (bf16_t*)(ws + 262144);           // 131,072 B
    bf16_t* vT  = (bf16_t*)(ws + 393216);           // 10,240,000 B
    bf16_t* slm = (bf16_t*)(ws + 10633216);         // 12,800,000 B
    bf16_t* Wvp = (bf16_t*)(ws + 23433216);         // 628 grp*16*4096 = 41,156,608 B
    bf16_t* W2p = (bf16_t*)(ws + 64589824);         // 784 grp*16*4096 = 51,380,224 B

    k_bn          <<<64,           256, 0, stream>>>(x, gamma, beta, xn);
    k_g1_packv    <<<64 + 2512,    256, 0, stream>>>(xn, W1, b1, h, Wslm, Wvp);
    k_gemm_v      <<<625,          256, 0, stream>>>(h, Wvp, bslm, vT);
    k_gather_packy<<<12500 + 3136, 256, 0, stream>>>(vT, slw, slidx, slm, W2, W2p);
    k_gemm_y      <<<782,          256, 0, stream>>>(h, W2p, b2, slm, out);
}

// Round 8
// 331.290 us; speedup vs baseline: 1.1352x; 1.0170x over previous
//
#include <hip/hip_runtime.h>

#define LL 64
#define DD 1024
#define HH 512
#define SS 50000
#define VV 40000
#define KD 32
#define MM 128  // B*L

typedef __bf16 bf16_t;
typedef __bf16 bf16x8 __attribute__((ext_vector_type(8)));
typedef __bf16 bf16x4 __attribute__((ext_vector_type(4)));
typedef __bf16 bf16x2 __attribute__((ext_vector_type(2)));
typedef float f32x4 __attribute__((ext_vector_type(4)));

__device__ __forceinline__ void async_ld16(const void* g, void* l) {
    __builtin_amdgcn_global_load_lds(
        (const __attribute__((address_space(1))) void*)g,
        (__attribute__((address_space(3))) void*)l, 16, 0, 0);
}

#define WAITV(N) asm volatile("s_waitcnt vmcnt(" #N ")" ::: "memory")

// ---------------- Kernel 1: BatchNorm over (B, D) per l; write xn bf16 [128][1024]
__global__ __launch_bounds__(256) void k_bn(const float* __restrict__ x,
        const float* __restrict__ gamma, const float* __restrict__ beta,
        bf16_t* __restrict__ xn) {
    int l = blockIdx.x;
    int t = threadIdx.x;
    int b = t >> 7;
    int d0 = (t & 127) << 3;
    const float* xp = x + (size_t)(b * LL + l) * DD + d0;
    float4 v0 = *(const float4*)xp;
    float4 v1 = *(const float4*)(xp + 4);
    float s  = v0.x + v0.y + v0.z + v0.w + v1.x + v1.y + v1.z + v1.w;
    float ss = v0.x*v0.x + v0.y*v0.y + v0.z*v0.z + v0.w*v0.w
             + v1.x*v1.x + v1.y*v1.y + v1.z*v1.z + v1.w*v1.w;
    #pragma unroll
    for (int off = 32; off > 0; off >>= 1) {
        s  += __shfl_xor(s, off);
        ss += __shfl_xor(ss, off);
    }
    __shared__ float red[8];
    int wv = t >> 6, ln = t & 63;
    if (ln == 0) { red[wv] = s; red[4 + wv] = ss; }
    __syncthreads();
    float tot  = red[0] + red[1] + red[2] + red[3];
    float tots = red[4] + red[5] + red[6] + red[7];
    float mean = tot * (1.0f / 2048.0f);
    float var  = tots * (1.0f / 2048.0f) - mean * mean;
    float rstd = rsqrtf(var + 1e-5f);
    float g   = gamma[l] * rstd;
    float ofs = beta[l] - mean * g;
    bf16x8 o;
    o[0] = (bf16_t)(v0.x * g + ofs);
    o[1] = (bf16_t)(v0.y * g + ofs);
    o[2] = (bf16_t)(v0.z * g + ofs);
    o[3] = (bf16_t)(v0.w * g + ofs);
    o[4] = (bf16_t)(v1.x * g + ofs);
    o[5] = (bf16_t)(v1.y * g + ofs);
    o[6] = (bf16_t)(v1.z * g + ofs);
    o[7] = (bf16_t)(v1.w * g + ofs);
    *(bf16x8*)(xn + (size_t)(b * LL + l) * DD + d0) = o;
}

// ---------------- Kernel 2: h = relu(xn @ W1 + b1), bf16 [128][512]
// 256 blocks x 1 wave; W1 re-reads hit L2 (W1 = 2 MB).
__global__ __launch_bounds__(64) void k_gemm1(const bf16_t* __restrict__ xn,
        const float* __restrict__ W1, const float* __restrict__ b1,
        bf16_t* __restrict__ h) {
    int lane = threadIdx.x & 63;
    int c = lane & 15, q = lane >> 4;
    int tile = blockIdx.x;           // 256 tiles: 8 m x 32 n
    int tm = tile >> 5, tn = tile & 31;
    int col = tn * 16 + c;
    f32x4 acc = {};
    #pragma unroll 2
    for (int kk = 0; kk < DD; kk += 32) {
        bf16x8 afr = *(const bf16x8*)(xn + (size_t)(tm * 16 + c) * DD + kk + q * 8);
        bf16x8 bfr;
        #pragma unroll
        for (int j = 0; j < 8; ++j)
            bfr[j] = (bf16_t)W1[(size_t)(kk + q * 8 + j) * HH + col];
        acc = __builtin_amdgcn_mfma_f32_16x16x32_bf16(afr, bfr, acc, 0, 0, 0);
    }
    float bias = b1[col];
    #pragma unroll
    for (int r = 0; r < 4; ++r) {
        int m = tm * 16 + q * 4 + r;   // C/D: col=lane&15, row=q*4+r  [m89]
        float v = acc[r] + bias;
        h[(size_t)m * HH + col] = (bf16_t)(v > 0.f ? v : 0.f);
    }
}

// ---------------- BN=32 high-TLP pipelined GEMM core ----------------
// Block: 256 threads, 32 output cols, all 128 rows. 24 KB LDS (2 x 12 KB:
// W fp32 [32k][32c] + h bf16 chunks). Grid >> 256 -> ~6 independent
// barrier-domains per CU; their stalls interleave (TLP covers HBM latency).
// dist-1 prefetch, counted vmcnt(3). h-chunk layout lane-consecutive
// (0 bank conflicts, measured r4). Wave wv owns rows [wv*32, wv*32+32).
__device__ __forceinline__ void gemm32_core(const bf16_t* __restrict__ A,
        const float* __restrict__ W, int NC, int nb, char* smem,
        f32x4 (&acc)[2][2]) {
    int t = threadIdx.x;
    int wrow = t >> 3, wcol = (t & 7) << 2;       // W: 1 chunk/thread
    bool ok = (nb + wcol + 4 <= NC);
    const float* gw = ok ? (W + (size_t)wrow * NC + nb + wcol) : W;
    int t2 = t + 256;                              // h: 2 chunks/thread
    const bf16_t* gh0 = A + (size_t)(((t  >> 6) << 4) + (t  & 15)) * HH + ((t  >> 4) & 3) * 8;
    const bf16_t* gh1 = A + (size_t)(((t2 >> 6) << 4) + (t2 & 15)) * HH + ((t2 >> 4) & 3) * 8;

    #define STG32(buf, st) do { \
        char* sb = smem + (buf) * 12288; \
        async_ld16(gw + (size_t)(st) * 32 * NC, sb + t * 16); \
        async_ld16(gh0 + (st) * 32, sb + 4096 + t * 16); \
        async_ld16(gh1 + (st) * 32, sb + 4096 + (t + 256) * 16); } while (0)

    STG32(0, 0); STG32(1, 1);      // 6 loads/thread in flight
    int lane = t & 63, wv = t >> 6;
    int c = lane & 15, q = lane >> 4;

    auto comp = [&](int cur) {
        char* sb = smem + cur * 12288;
        const float*  wl = (const float*)sb;
        const bf16_t* al = (const bf16_t*)(sb + 4096);
        bf16x8 bfr0, bfr1;
        #pragma unroll
        for (int j = 0; j < 8; ++j) {
            bfr0[j] = (bf16_t)wl[(q * 8 + j) * 32 + c];
            bfr1[j] = (bf16_t)wl[(q * 8 + j) * 32 + 16 + c];
        }
        #pragma unroll
        for (int m2 = 0; m2 < 2; ++m2) {
            bf16x8 afr = *(const bf16x8*)(al + (size_t)((wv * 2 + m2) * 64 + lane) * 8);
            acc[m2][0] = __builtin_amdgcn_mfma_f32_16x16x32_bf16(afr, bfr0, acc[m2][0], 0, 0, 0);
            acc[m2][1] = __builtin_amdgcn_mfma_f32_16x16x32_bf16(afr, bfr1, acc[m2][1], 0, 0, 0);
        }
    };

    #pragma unroll 1
    for (int st = 0; st < 14; ++st) {
        WAITV(3);                       // own stage[st] landed; next in flight
        __builtin_amdgcn_s_barrier();   // buffer complete across waves
        comp(st & 1);
        __builtin_amdgcn_s_barrier();   // all waves done reading before reuse
        STG32(st & 1, st + 2);
    }
    WAITV(3); __builtin_amdgcn_s_barrier(); comp(0);   // st=14
    WAITV(0); __builtin_amdgcn_s_barrier(); comp(1);   // st=15
    #undef STG32
}

// ---------------- Kernel 3: vT[col][m] = bf16(h @ Wslm + bslm)
__global__ __launch_bounds__(256) void k_gemm_v(const bf16_t* __restrict__ h,
        const float* __restrict__ Wslm, const float* __restrict__ bslm,
        bf16_t* __restrict__ vT) {
    __shared__ __align__(16) char smem[2 * 12288];   // 24 KB
    int nb = blockIdx.x * 32;          // 1250 * 32 = 40000 exact
    f32x4 acc[2][2] = {};
    gemm32_core(h, Wslm, VV, nb, smem, acc);
    int t = threadIdx.x, lane = t & 63, wv = t >> 6;
    int c = lane & 15, q = lane >> 4;
    #pragma unroll
    for (int ns = 0; ns < 2; ++ns) {
        int col = nb + ns * 16 + c;
        float bias = bslm[col];
        #pragma unroll
        for (int m2 = 0; m2 < 2; ++m2) {
            int mr = (wv * 2 + m2) * 16 + q * 4;
            bf16x4 o;
            #pragma unroll
            for (int rr = 0; rr < 4; ++rr) o[rr] = (bf16_t)(acc[m2][ns][rr] + bias);
            *(bf16x4*)(vT + (size_t)col * MM + mr) = o;
        }
    }
}

// ---------------- Kernel 4: gather — one wave per s, lane owns 2 m-values.
// vT (10 MB) is L3-resident; keep this kernel free of streaming co-tenants.
__global__ __launch_bounds__(256) void k_gather(const bf16_t* __restrict__ vT,
        const float* __restrict__ slw, const int* __restrict__ slidx,
        bf16_t* __restrict__ slm) {
    int t = threadIdx.x;
    int wv = t >> 6, lane = t & 63;
    int s = blockIdx.x * 4 + wv;        // 50000 = 12500*4, exact
    int idv = slidx[(size_t)s * KD + (lane & 31)];
    float wgt = slw[(size_t)s * KD + (lane & 31)];
    unsigned int u[KD];
    #pragma unroll
    for (int k = 0; k < KD; ++k) {
        int id = __shfl(idv, k);
        u[k] = *(const unsigned int*)(vT + (size_t)id * MM + lane * 2);
    }
    float a0 = 0.f, a1 = 0.f;
    #pragma unroll
    for (int k = 0; k < KD; ++k) {
        float w = __shfl(wgt, k);
        a0 += w * __uint_as_float(u[k] << 16);
        a1 += w * __uint_as_float(u[k] & 0xffff0000u);
    }
    bf16x2 o;
    o[0] = (bf16_t)a0;
    o[1] = (bf16_t)a1;
    *(bf16x2*)(slm + (size_t)s * MM + lane * 2) = o;
}

// ---------------- Kernel 5: out = h @ W2 + b2 + 0.1 * slm^T
__global__ __launch_bounds__(256) void k_gemm_y(const bf16_t* __restrict__ h,
        const float* __restrict__ W2, const float* __restrict__ b2,
        const bf16_t* __restrict__ slm, float* __restrict__ out) {
    __shared__ __align__(16) char smem[2 * 12288];   // 24 KB
    int nb = blockIdx.x * 32;          // 1563 blocks -> 50016 cols, guarded
    f32x4 acc[2][2] = {};
    gemm32_core(h, W2, SS, nb, smem, acc);
    int t = threadIdx.x, lane = t & 63, wv = t >> 6;
    int c = lane & 15, q = lane >> 4;
    #pragma unroll
    for (int ns = 0; ns < 2; ++ns) {
        int col = nb + ns * 16 + c;
        if (col < SS) {
            float bias = b2[col];
            #pragma unroll
            for (int m2 = 0; m2 < 2; ++m2) {
                int mr = (wv * 2 + m2) * 16 + q * 4;
                bf16x4 sv = *(const bf16x4*)(slm + (size_t)col * MM + mr);
                #pragma unroll
                for (int rr = 0; rr < 4; ++rr)
                    out[(size_t)(mr + rr) * SS + col] = acc[m2][ns][rr] + bias
                                                        + 0.1f * (float)sv[rr];
            }
        }
    }
}

extern "C" void kernel_launch(void* const* d_in, const int* in_sizes, int n_in,
                              void* d_out, int out_size, void* d_ws, size_t ws_size,
                              hipStream_t stream) {
    const float* x     = (const float*)d_in[0];
    const float* gamma = (const float*)d_in[1];
    const float* beta  = (const float*)d_in[2];
    const float* W1    = (const float*)d_in[3];
    const float* b1    = (const float*)d_in[4];
    const float* W2    = (const float*)d_in[5];
    const float* b2    = (const float*)d_in[6];
    const float* Wslm  = (const float*)d_in[7];
    const float* bslm  = (const float*)d_in[8];
    const float* slw   = (const float*)d_in[9];
    const int*   slidx = (const int*)d_in[10];
    float* out = (float*)d_out;

    char* ws = (char*)d_ws;
    bf16_t* xn  = (bf16_t*)ws;                     // 128*1024*2  = 262144 B
    bf16_t* h   = (bf16_t*)(ws + 262144);          // 128*512*2   = 131072 B
    bf16_t* vT  = (bf16_t*)(ws + 393216);          // 40000*128*2 = 10240000 B
    bf16_t* slm = (bf16_t*)(ws + 10633216);        // 50000*128*2 = 12800000 B

    k_bn    <<<64,    256, 0, stream>>>(x, gamma, beta, xn);
    k_gemm1 <<<256,   64,  0, stream>>>(xn, W1, b1, h);
    k_gemm_v<<<1250,  256, 0, stream>>>(h, Wslm, bslm, vT);
    k_gather<<<12500, 256, 0, stream>>>(vT, slw, slidx, slm);
    k_gemm_y<<<1563,  256, 0, stream>>>(h, W2, b2, slm, out);
}